// Round 1
// baseline (822.501 us; speedup 1.0000x reference)
//
#include <hip/hip_runtime.h>
#include <math.h>

#define DEV __device__ __forceinline__

DEV float leakyf(float v) { return v >= 0.f ? v : 0.01f * v; }

// Direct convolution, thread per output element (NCHW, OIHW weights).
// ACT: 0 = leaky relu
template<int CIN, int COUT, int K, int S, int P, int HIN, int HOUT>
__global__ __launch_bounds__(256) void conv_k(const float* __restrict__ in,
                                              const float* __restrict__ w,
                                              const float* __restrict__ b,
                                              float* __restrict__ out, int total)
{
    int idx = blockIdx.x * 256 + threadIdx.x;
    if (idx >= total) return;
    int x  = idx % HOUT;
    int y  = (idx / HOUT) % HOUT;
    int co = (idx / (HOUT * HOUT)) % COUT;
    int n  = idx / (HOUT * HOUT * COUT);
    float acc = b[co];
    const float* inn = in + n * CIN * HIN * HIN;
    #pragma unroll
    for (int ci = 0; ci < CIN; ++ci) {
        const float* inc = inn + ci * HIN * HIN;
        const float* wc  = w + ((co * CIN + ci) * K) * K;
        #pragma unroll
        for (int ky = 0; ky < K; ++ky) {
            int iy = y * S - P + ky;
            if (iy < 0 || iy >= HIN) continue;
            #pragma unroll
            for (int kx = 0; kx < K; ++kx) {
                int ix = x * S - P + kx;
                if (ix < 0 || ix >= HIN) continue;
                acc = fmaf(inc[iy * HIN + ix], wc[ky * K + kx], acc);
            }
        }
    }
    out[idx] = leakyf(acc);
}

// Transposed convolution (gather form), PyTorch ConvT weight layout (Cin, Cout, K, K).
// ACT: 0 = leaky, 1 = tanh
template<int CIN, int COUT, int K, int S, int P, int HIN, int HOUT, int ACT>
__global__ __launch_bounds__(256) void convt_k(const float* __restrict__ in,
                                               const float* __restrict__ w,
                                               const float* __restrict__ b,
                                               float* __restrict__ out, int total)
{
    int idx = blockIdx.x * 256 + threadIdx.x;
    if (idx >= total) return;
    int x  = idx % HOUT;
    int y  = (idx / HOUT) % HOUT;
    int co = (idx / (HOUT * HOUT)) % COUT;
    int n  = idx / (HOUT * HOUT * COUT);
    float acc = b[co];
    const float* inn = in + n * CIN * HIN * HIN;
    #pragma unroll
    for (int ky = 0; ky < K; ++ky) {
        int ty = y + P - ky;
        if (ty < 0 || (ty % S) != 0) continue;
        int iy = ty / S;
        if (iy >= HIN) continue;
        #pragma unroll
        for (int kx = 0; kx < K; ++kx) {
            int tx = x + P - kx;
            if (tx < 0 || (tx % S) != 0) continue;
            int ix = tx / S;
            if (ix >= HIN) continue;
            #pragma unroll
            for (int ci = 0; ci < CIN; ++ci) {
                acc = fmaf(inn[ci * HIN * HIN + iy * HIN + ix],
                           w[((ci * COUT + co) * K + ky) * K + kx], acc);
            }
        }
    }
    out[idx] = (ACT == 0) ? leakyf(acc) : tanhf(acc);
}

// Precompute |c_k|^2 for each codebook row.
__global__ void c2_k(const float* __restrict__ cb, float* __restrict__ c2)
{
    int k = blockIdx.x * blockDim.x + threadIdx.x;
    if (k >= 512) return;
    float s = 0.f;
    #pragma unroll
    for (int j = 0; j < 64; ++j) { float v = cb[k * 64 + j]; s = fmaf(v, v, s); }
    c2[k] = s;
}

// VQ: per-thread one latent row (D=64 in registers), codebook chunked via LDS.
// Writes quantized output (NCHW) and accumulates sum((q - lat)^2) into lossAcc.
__global__ __launch_bounds__(256) void vq_k(const float* __restrict__ lat,
                                            const float* __restrict__ cb,
                                            const float* __restrict__ c2g,
                                            float* __restrict__ q,
                                            float* __restrict__ lossAcc)
{
    __shared__ float cbs[64 * 64];   // 64 codes per chunk
    __shared__ float c2s[64];
    int m = blockIdx.x * 256 + threadIdx.x;      // 65536 rows exactly
    int base = (m >> 10) * 65536 + (m & 1023);   // NCHW: n*64*1024 + (y*32+x)
    float f[64];
    #pragma unroll
    for (int j = 0; j < 64; ++j) f[j] = lat[base + j * 1024];

    float best = 3.4e38f;
    int bestk = 0;
    for (int ch = 0; ch < 8; ++ch) {
        __syncthreads();
        #pragma unroll
        for (int i = 0; i < 16; ++i)
            cbs[threadIdx.x + i * 256] = cb[ch * 4096 + threadIdx.x + i * 256];
        if (threadIdx.x < 64) c2s[threadIdx.x] = c2g[ch * 64 + threadIdx.x];
        __syncthreads();
        for (int kk = 0; kk < 64; ++kk) {
            float acc = 0.f;
            #pragma unroll
            for (int j = 0; j < 64; ++j) acc = fmaf(f[j], cbs[kk * 64 + j], acc);
            float score = 0.5f * c2s[kk] - acc;   // argmin-equivalent distance
            if (score < best) { best = score; bestk = ch * 64 + kk; }
        }
    }

    // gather codebook row -> q (NCHW), fused loss accumulation
    float rs = 0.f;
    #pragma unroll
    for (int j = 0; j < 64; ++j) {
        float c = cb[bestk * 64 + j];
        q[base + j * 1024] = c;
        float d = c - f[j];
        rs = fmaf(d, d, rs);
    }
    #pragma unroll
    for (int off = 32; off; off >>= 1) rs += __shfl_down(rs, off, 64);
    if ((threadIdx.x & 63) == 0) atomicAdd(lossAcc, rs);
}

__global__ void loss_k(const float* __restrict__ acc, float* __restrict__ out)
{
    // vq_loss = (1 + beta) * mean((q - lat)^2), beta = 0.25
    out[0] = 1.25f * acc[0] / 4194304.0f;
}

extern "C" void kernel_launch(void* const* d_in, const int* in_sizes, int n_in,
                              void* d_out, int out_size, void* d_ws, size_t ws_size,
                              hipStream_t stream)
{
    const float* x        = (const float*)d_in[0];
    const float* ew1      = (const float*)d_in[1];
    const float* eb1      = (const float*)d_in[2];
    const float* ew2      = (const float*)d_in[3];
    const float* eb2      = (const float*)d_in[4];
    const float* ew3      = (const float*)d_in[5];
    const float* eb3      = (const float*)d_in[6];
    const float* ew4      = (const float*)d_in[7];
    const float* eb4      = (const float*)d_in[8];
    const float* codebook = (const float*)d_in[9];
    const float* dw1      = (const float*)d_in[10];
    const float* db1      = (const float*)d_in[11];
    const float* dw2      = (const float*)d_in[12];
    const float* db2      = (const float*)d_in[13];
    const float* dw3      = (const float*)d_in[14];
    const float* db3      = (const float*)d_in[15];

    float* out = (float*)d_out;
    float* ws  = (float*)d_ws;
    const size_t BUF = 4194304;           // 16.78 MB each
    float* A       = ws;                  // h1 (2.1M) / latents (4.2M) / d2out (2.1M)
    float* B       = ws + BUF;            // h2 (1.05M) / q (4.2M)
    float* C       = ws + 2 * BUF;        // h3 (1.05M) / d1out (1.05M)
    float* c2g     = ws + 3 * BUF;        // 512 floats
    float* lossAcc = ws + 3 * BUF + 512;  // 1 float

    hipMemsetAsync(lossAcc, 0, sizeof(float), stream);

    // encoder
    conv_k<1, 8, 4, 2, 1, 128, 64><<<8192, 256, 0, stream>>>(x, ew1, eb1, A, 2097152);
    conv_k<8, 16, 4, 2, 1, 64, 32><<<4096, 256, 0, stream>>>(A, ew2, eb2, B, 1048576);
    conv_k<16, 16, 3, 1, 1, 32, 32><<<4096, 256, 0, stream>>>(B, ew3, eb3, C, 1048576);
    conv_k<16, 64, 1, 1, 0, 32, 32><<<16384, 256, 0, stream>>>(C, ew4, eb4, A, 4194304);

    // vector quantization
    c2_k<<<2, 256, 0, stream>>>(codebook, c2g);
    vq_k<<<256, 256, 0, stream>>>(A, codebook, c2g, B, lossAcc);

    // decoder
    conv_k<64, 16, 3, 1, 1, 32, 32><<<4096, 256, 0, stream>>>(B, dw1, db1, C, 1048576);
    convt_k<16, 8, 4, 2, 1, 32, 64, 0><<<8192, 256, 0, stream>>>(C, dw2, db2, A, 2097152);
    convt_k<8, 1, 4, 2, 1, 64, 128, 1><<<4096, 256, 0, stream>>>(A, dw3, db3, out, 1048576);

    loss_k<<<1, 1, 0, stream>>>(lossAcc, out + 1048576);
}

// Round 2
// 243.760 us; speedup vs baseline: 3.3742x; 3.3742x over previous
//
#include <hip/hip_runtime.h>
#include <math.h>

#define DEV __device__ __forceinline__

DEV float leakyf(float v) { return v >= 0.f ? v : 0.01f * v; }

// ---------------- forward conv: thread = one spatial pos, COB channels ------
template<int CIN, int COUT, int COB, int K, int S, int P, int HIN, int HOUT>
__global__ __launch_bounds__(256) void convf_k(const float* __restrict__ in,
                                               const float* __restrict__ w,
                                               const float* __restrict__ b,
                                               float* __restrict__ out)
{
    constexpr int NCG = COUT / COB;
    constexpr int WSZ = CIN * K * K * COB;
    __shared__ float wl[WSZ];
    int t = threadIdx.x;
    int idx = blockIdx.x * 256 + t;
    int x  = idx % HOUT;
    int y  = (idx / HOUT) % HOUT;
    int cg = (idx / (HOUT * HOUT)) % NCG;      // uniform per block (HOUT*HOUT >= 1024)
    int n  = idx / (HOUT * HOUT * NCG);

    for (int i = t; i < WSZ; i += 256) {
        int co = i % COB;
        int r  = i / COB;
        int kx = r % K, ky = (r / K) % K, ci = r / (K * K);
        wl[i] = w[(((cg * COB + co) * CIN + ci) * K + ky) * K + kx];
    }
    __syncthreads();

    float acc[COB];
    #pragma unroll
    for (int j = 0; j < COB; ++j) acc[j] = b[cg * COB + j];

    const float* inn = in + n * CIN * HIN * HIN;
    for (int ci = 0; ci < CIN; ++ci) {
        #pragma unroll
        for (int ky = 0; ky < K; ++ky) {
            int iy = y * S - P + ky;
            bool vy = (iy >= 0) && (iy < HIN);
            #pragma unroll
            for (int kx = 0; kx < K; ++kx) {
                int ix = x * S - P + kx;
                float v = (vy && ix >= 0 && ix < HIN) ? inn[(ci * HIN + iy) * HIN + ix] : 0.f;
                const float* wp = &wl[((ci * K + ky) * K + kx) * COB];
                if constexpr (COB % 4 == 0) {
                    #pragma unroll
                    for (int j4 = 0; j4 < COB / 4; ++j4) {
                        float4 wv = *(const float4*)(wp + j4 * 4);
                        acc[j4 * 4 + 0] = fmaf(v, wv.x, acc[j4 * 4 + 0]);
                        acc[j4 * 4 + 1] = fmaf(v, wv.y, acc[j4 * 4 + 1]);
                        acc[j4 * 4 + 2] = fmaf(v, wv.z, acc[j4 * 4 + 2]);
                        acc[j4 * 4 + 3] = fmaf(v, wv.w, acc[j4 * 4 + 3]);
                    }
                } else {
                    #pragma unroll
                    for (int j = 0; j < COB; ++j) acc[j] = fmaf(v, wp[j], acc[j]);
                }
            }
        }
    }
    #pragma unroll
    for (int j = 0; j < COB; ++j)
        out[((n * COUT + cg * COB + j) * HOUT + y) * HOUT + x] = leakyf(acc[j]);
}

// ---------------- transposed conv (gather), PyTorch ConvT weights (Cin,Cout,K,K)
template<int CIN, int COUT, int COB, int K, int S, int P, int HIN, int HOUT, int ACT>
__global__ __launch_bounds__(256) void convtf_k(const float* __restrict__ in,
                                                const float* __restrict__ w,
                                                const float* __restrict__ b,
                                                float* __restrict__ out)
{
    constexpr int NCG = COUT / COB;
    constexpr int WSZ = CIN * K * K * COB;
    constexpr int NTAP = K / S;
    __shared__ float wl[WSZ];
    int t = threadIdx.x;
    int idx = blockIdx.x * 256 + t;
    int x  = idx % HOUT;
    int y  = (idx / HOUT) % HOUT;
    int cg = (idx / (HOUT * HOUT)) % NCG;
    int n  = idx / (HOUT * HOUT * NCG);

    for (int i = t; i < WSZ; i += 256) {
        int co = i % COB;
        int r  = i / COB;
        int kx = r % K, ky = (r / K) % K, ci = r / (K * K);
        wl[i] = w[((ci * COUT + cg * COB + co) * K + ky) * K + kx];
    }
    __syncthreads();

    float acc[COB];
    #pragma unroll
    for (int j = 0; j < COB; ++j) acc[j] = b[cg * COB + j];

    int py = (y + P) % S;
    int px = (x + P) % S;
    const float* inn = in + n * CIN * HIN * HIN;
    for (int ci = 0; ci < CIN; ++ci) {
        #pragma unroll
        for (int ty = 0; ty < NTAP; ++ty) {
            int ky = py + ty * S;
            int iy = (y + P - ky) / S;
            bool vy = (ky < K) && (iy >= 0) && (iy < HIN);
            #pragma unroll
            for (int tx = 0; tx < NTAP; ++tx) {
                int kx = px + tx * S;
                int ix = (x + P - kx) / S;
                float v = (vy && kx < K && ix >= 0 && ix < HIN)
                              ? inn[(ci * HIN + iy) * HIN + ix] : 0.f;
                const float* wp = &wl[((ci * K + ky) * K + kx) * COB];
                if constexpr (COB % 4 == 0) {
                    #pragma unroll
                    for (int j4 = 0; j4 < COB / 4; ++j4) {
                        float4 wv = *(const float4*)(wp + j4 * 4);
                        acc[j4 * 4 + 0] = fmaf(v, wv.x, acc[j4 * 4 + 0]);
                        acc[j4 * 4 + 1] = fmaf(v, wv.y, acc[j4 * 4 + 1]);
                        acc[j4 * 4 + 2] = fmaf(v, wv.z, acc[j4 * 4 + 2]);
                        acc[j4 * 4 + 3] = fmaf(v, wv.w, acc[j4 * 4 + 3]);
                    }
                } else {
                    #pragma unroll
                    for (int j = 0; j < COB; ++j) acc[j] = fmaf(v, wp[j], acc[j]);
                }
            }
        }
    }
    #pragma unroll
    for (int j = 0; j < COB; ++j) {
        float r = acc[j];
        out[((n * COUT + cg * COB + j) * HOUT + y) * HOUT + x] =
            (ACT == 0) ? leakyf(r) : tanhf(r);
    }
}

// ---------------- codebook helpers ----------------
__global__ void c2_k(const float* __restrict__ cb, float* __restrict__ c2)
{
    int k = blockIdx.x * blockDim.x + threadIdx.x;
    if (k >= 512) return;
    float s = 0.f;
    #pragma unroll
    for (int j = 0; j < 64; ++j) { float v = cb[k * 64 + j]; s = fmaf(v, v, s); }
    c2[k] = s;
}

__global__ void tr_k(const float* __restrict__ cb, float* __restrict__ ct)
{
    int i = blockIdx.x * 256 + threadIdx.x;    // 32768 elements: ct[d*512+k]
    int d = i >> 9, k = i & 511;
    ct[i] = cb[k * 64 + d];
}

// ---------------- VQ as tiled GEMM: block = 64 rows x 512 codes -------------
__global__ __launch_bounds__(256) void vq2_k(const float* __restrict__ lat,
                                             const float* __restrict__ ct,
                                             const float* __restrict__ cb,
                                             const float* __restrict__ c2g,
                                             float* __restrict__ q,
                                             float* __restrict__ lossAcc)
{
    __shared__ float Fs[64 * 64];      // [d][row]
    __shared__ float Cs[64 * 64];      // [d][code'], later aliased for reduction
    __shared__ float c2s[64];
    __shared__ int   bidx[64];

    int t = threadIdx.x;
    int b = blockIdx.x;                // 1024 blocks
    int n = b >> 4;
    int pos0 = (b & 15) << 6;
    const float* latb = lat + n * 65536 + pos0;

    #pragma unroll
    for (int i = 0; i < 16; ++i) {
        int flat = i * 256 + t;
        Fs[flat] = latb[(flat >> 6) * 1024 + (flat & 63)];
    }

    int tr = t & 15, tc = t >> 4;      // 4 rows each, 4 codes each per chunk
    float best[4]; int bk[4];
    #pragma unroll
    for (int i = 0; i < 4; ++i) { best[i] = 3.4e38f; bk[i] = 0; }

    for (int ch = 0; ch < 8; ++ch) {
        __syncthreads();
        #pragma unroll
        for (int i = 0; i < 16; ++i) {
            int flat = i * 256 + t;
            Cs[flat] = ct[(flat >> 6) * 512 + ch * 64 + (flat & 63)];
        }
        if (t < 64) c2s[t] = c2g[ch * 64 + t];
        __syncthreads();

        float dot[4][4] = {};
        #pragma unroll 16
        for (int d = 0; d < 64; ++d) {
            float4 fv = *(const float4*)&Fs[d * 64 + tr * 4];
            float4 cv = *(const float4*)&Cs[d * 64 + tc * 4];
            dot[0][0] = fmaf(fv.x, cv.x, dot[0][0]);
            dot[0][1] = fmaf(fv.x, cv.y, dot[0][1]);
            dot[0][2] = fmaf(fv.x, cv.z, dot[0][2]);
            dot[0][3] = fmaf(fv.x, cv.w, dot[0][3]);
            dot[1][0] = fmaf(fv.y, cv.x, dot[1][0]);
            dot[1][1] = fmaf(fv.y, cv.y, dot[1][1]);
            dot[1][2] = fmaf(fv.y, cv.z, dot[1][2]);
            dot[1][3] = fmaf(fv.y, cv.w, dot[1][3]);
            dot[2][0] = fmaf(fv.z, cv.x, dot[2][0]);
            dot[2][1] = fmaf(fv.z, cv.y, dot[2][1]);
            dot[2][2] = fmaf(fv.z, cv.z, dot[2][2]);
            dot[2][3] = fmaf(fv.z, cv.w, dot[2][3]);
            dot[3][0] = fmaf(fv.w, cv.x, dot[3][0]);
            dot[3][1] = fmaf(fv.w, cv.y, dot[3][1]);
            dot[3][2] = fmaf(fv.w, cv.z, dot[3][2]);
            dot[3][3] = fmaf(fv.w, cv.w, dot[3][3]);
        }
        #pragma unroll
        for (int j = 0; j < 4; ++j) {
            float hc2 = 0.5f * c2s[tc * 4 + j];
            int idx = ch * 64 + tc * 4 + j;
            #pragma unroll
            for (int i = 0; i < 4; ++i) {
                float s = hc2 - dot[i][j];
                if (s < best[i]) { best[i] = s; bk[i] = idx; }
            }
        }
    }

    __syncthreads();                   // all Cs reads done before aliasing
    float* redS = Cs;                  // [row][16]
    int*   redI = (int*)(Cs + 1024);
    #pragma unroll
    for (int i = 0; i < 4; ++i) {
        int r = tr * 4 + i;
        redS[r * 16 + tc] = best[i];
        redI[r * 16 + tc] = bk[i];
    }
    __syncthreads();
    if (t < 64) {
        float bs = redS[t * 16]; int bi = redI[t * 16];
        #pragma unroll
        for (int c = 1; c < 16; ++c) {
            float s = redS[t * 16 + c]; int ii = redI[t * 16 + c];
            if (s < bs || (s == bs && ii < bi)) { bs = s; bi = ii; }
        }
        bidx[t] = bi;
    }
    __syncthreads();

    float rs = 0.f;
    #pragma unroll
    for (int i = 0; i < 16; ++i) {
        int flat = i * 256 + t;
        int d = flat >> 6, r = flat & 63;
        float c = cb[bidx[r] * 64 + d];
        q[n * 65536 + d * 1024 + pos0 + r] = c;
        float dd = c - Fs[d * 64 + r];
        rs = fmaf(dd, dd, rs);
    }
    #pragma unroll
    for (int off = 32; off; off >>= 1) rs += __shfl_down(rs, off, 64);
    if ((t & 63) == 0) atomicAdd(lossAcc, rs);
}

__global__ void loss_k(const float* __restrict__ acc, float* __restrict__ out)
{
    out[0] = 1.25f * acc[0] / 4194304.0f;
}

extern "C" void kernel_launch(void* const* d_in, const int* in_sizes, int n_in,
                              void* d_out, int out_size, void* d_ws, size_t ws_size,
                              hipStream_t stream)
{
    const float* x        = (const float*)d_in[0];
    const float* ew1      = (const float*)d_in[1];
    const float* eb1      = (const float*)d_in[2];
    const float* ew2      = (const float*)d_in[3];
    const float* eb2      = (const float*)d_in[4];
    const float* ew3      = (const float*)d_in[5];
    const float* eb3      = (const float*)d_in[6];
    const float* ew4      = (const float*)d_in[7];
    const float* eb4      = (const float*)d_in[8];
    const float* codebook = (const float*)d_in[9];
    const float* dw1      = (const float*)d_in[10];
    const float* db1      = (const float*)d_in[11];
    const float* dw2      = (const float*)d_in[12];
    const float* db2      = (const float*)d_in[13];
    const float* dw3      = (const float*)d_in[14];
    const float* db3      = (const float*)d_in[15];

    float* out = (float*)d_out;
    float* ws  = (float*)d_ws;
    float* A       = ws;                 // h1 (2.1M) / latents (4.2M) / d2out (2.1M)
    float* B       = ws + 4194304;       // h2 (1.05M) / q (4.2M)
    float* C       = ws + 8388608;       // h3 (1.05M) / d1out (1.05M)
    float* c2g     = ws + 9437184;       // 512
    float* lossAcc = ws + 9437696;       // 1
    float* CT      = ws + 9438208;       // 32768 (codebook transposed [64][512])

    hipMemsetAsync(lossAcc, 0, sizeof(float), stream);
    tr_k<<<128, 256, 0, stream>>>(codebook, CT);
    c2_k<<<2, 256, 0, stream>>>(codebook, c2g);

    // encoder
    convf_k<1, 8, 8, 4, 2, 1, 128, 64><<<1024, 256, 0, stream>>>(x, ew1, eb1, A);
    convf_k<8, 16, 4, 4, 2, 1, 64, 32><<<1024, 256, 0, stream>>>(A, ew2, eb2, B);
    convf_k<16, 16, 4, 3, 1, 1, 32, 32><<<1024, 256, 0, stream>>>(B, ew3, eb3, C);
    convf_k<16, 64, 16, 1, 1, 0, 32, 32><<<1024, 256, 0, stream>>>(C, ew4, eb4, A);

    // vector quantization
    vq2_k<<<1024, 256, 0, stream>>>(A, CT, codebook, c2g, B, lossAcc);

    // decoder
    convf_k<64, 16, 4, 3, 1, 1, 32, 32><<<1024, 256, 0, stream>>>(B, dw1, db1, C);
    convtf_k<16, 8, 8, 4, 2, 1, 32, 64, 0><<<1024, 256, 0, stream>>>(C, dw2, db2, A);
    convtf_k<8, 1, 1, 4, 2, 1, 64, 128, 1><<<4096, 256, 0, stream>>>(A, dw3, db3, out);

    loss_k<<<1, 1, 0, stream>>>(lossAcc, out + 1048576);
}